// Round 9
// baseline (3620.767 us; speedup 1.0000x reference)
//
#include <hip/hip_runtime.h>
#include <math.h>

#define T_STEPS 1024
#define BATCH   512
#define DZ      256
#define DH      256
#define RANK    8
#define DY      16

// 512 blocks x 512 threads (8 waves), 1 batch element/block.
// 3-barrier structure (validated, absmax 0.0039):
//   A -> {dot2 partials, out(t-1), tanh(h)@V} -> B
//     -> {z-update (waves 0-3) || rz/sig/gl (waves 4-7)} -> C
//     -> {h-update, input publish} -> A
//
// REGISTER INCANTATION (R1-R8): __launch_bounds__(512, 2) -> 108-112 VGPRs,
// no spills (verified R6/R8). (512,4)/(1024,*) cap at 64/32 and spill. Do
// not touch.
//
// LDS BUDGET (R8 lesson): at 47 KB LDS only 1 block/CU was resident
// (OccupancyPercent 24.4 = 8 waves/CU) and the grid ran as two sequential
// passes -> 2x duration. All step-loop matrices are f16 now (~25 KB total)
// so 2 blocks/CU co-reside even under a 64 KB-pool assumption; the
// co-resident block hides barrier/LDS latency.

typedef _Float16 f16;
typedef _Float16 h2 __attribute__((ext_vector_type(2)));

__device__ __forceinline__ h2 pack2(float a, float b) {
    h2 r; r.x = (f16)a; r.y = (f16)b; return r;
}
__device__ __forceinline__ h2 bc(unsigned u) { return __builtin_bit_cast(h2, u); }

__device__ __forceinline__ float dot2(h2 a, h2 b, float c) {
#if __has_builtin(__builtin_amdgcn_fdot2)
    return __builtin_amdgcn_fdot2(a, b, c, false);
#else
    return fmaf((float)a.x, (float)b.x, fmaf((float)a.y, (float)b.y, c));
#endif
}

__device__ __forceinline__ float fast_tanh(float x) {
    const float e = __expf(2.0f * x);
    return 1.0f - 2.0f / (e + 1.0f);
}

__global__ __launch_bounds__(512, 2)
void nmrnn_kernel(
    const float* __restrict__ s, const float* __restrict__ c,
    const float* __restrict__ W_zz, const float* __restrict__ Wz_in,
    const float* __restrict__ bz_in, const float* __restrict__ Wz_out,
    const float* __restrict__ bz_out, const float* __restrict__ U,
    const float* __restrict__ V, const float* __restrict__ W_in,
    const float* __restrict__ b_in, const float* __restrict__ W_out,
    const float* __restrict__ b_out,
    float* __restrict__ out, float* __restrict__ states)
{
    __shared__ __align__(16) f16 tzh[DZ];        // tanh(z) f16         512 B
    __shared__ __align__(16) f16 thh[DH];        // tanh(h) f16         512 B
    __shared__ __align__(16) f16 sclh[64];       // [s_t|c_t] f16       128 B
    __shared__ __align__(16) float redz[2][DZ];  // z-dot partials      2 KB
    __shared__ __align__(16) float redh[2][DZ];  // W_in-dot partials   2 KB
    __shared__ __align__(16) f16 wzo16[RANK][DZ];// Wz_out f16          4 KB
    __shared__ __align__(16) f16 vt16[RANK][DH]; // V^T f16             4 KB
    __shared__ __align__(16) f16 ut16[RANK][DH]; // U^T f16             4 KB
    __shared__ __align__(16) f16 wo16[DY][DH];   // W_out f16           8 KB
    __shared__ float gl[RANK];
    __shared__ float bo[DY];
    // total ~25.3 KB

    const int tid  = threadIdx.x;
    const int i    = tid & 255;
    const int q2   = tid >> 8;     // 0..1  K-half
    const int g    = tid >> 6;     // 0..7  wave
    const int l    = tid & 63;
    const int half = l >> 5;
    const int l32  = l & 31;
    const int b    = blockIdx.x;

    // ---- persistent f16-packed weights (88 VGPRs) ----
    h2 wzzp[64];
    #pragma unroll
    for (int m = 0; m < 32; ++m) {
        const float4 v4 = *(const float4*)&W_zz[i * 256 + (q2 << 7) + (m << 2)];
        wzzp[2 * m]     = pack2(v4.x, v4.y);
        wzzp[2 * m + 1] = pack2(v4.z, v4.w);
    }
    h2 wzip[16];
    #pragma unroll
    for (int m = 0; m < 8; ++m) {
        const float4 v4 = *(const float4*)&Wz_in[i * 64 + (q2 << 5) + (m << 2)];
        wzip[2 * m]     = pack2(v4.x, v4.y);
        wzip[2 * m + 1] = pack2(v4.z, v4.w);
    }
    h2 wip[8];
    #pragma unroll
    for (int m = 0; m < 4; ++m) {
        const float4 v4 = *(const float4*)&W_in[i * 32 + (q2 << 4) + (m << 2)];
        wip[2 * m]     = pack2(v4.x, v4.y);
        wip[2 * m + 1] = pack2(v4.z, v4.w);
    }

    // ---- stage small matrices as f16 ----
    {   // Wz_out: 2048 floats -> wzo16
        const int idx = tid * 4;
        const float4 v4 = *(const float4*)&Wz_out[idx];
        h2* dst = (h2*)&((f16*)wzo16)[idx];
        dst[0] = pack2(v4.x, v4.y);
        dst[1] = pack2(v4.z, v4.w);
    }
    #pragma unroll
    for (int it = 0; it < 2; ++it) {  // W_out: 4096 floats -> wo16
        const int idx = tid * 4 + it * 2048;
        const float4 v4 = *(const float4*)&W_out[idx];
        h2* dst = (h2*)&((f16*)wo16)[idx];
        dst[0] = pack2(v4.x, v4.y);
        dst[1] = pack2(v4.z, v4.w);
    }
    if (tid < 256) {  // transpose V, U -> f16
        #pragma unroll
        for (int r = 0; r < RANK; ++r) vt16[r][tid] = (f16)V[tid * RANK + r];
        #pragma unroll
        for (int r = 0; r < RANK; ++r) ut16[r][tid] = (f16)U[tid * RANK + r];
        tzh[tid] = (f16)0.f; thh[tid] = (f16)0.f;
    }
    if (tid < DY) bo[tid] = b_out[tid];

    const float bzi = (tid < 256) ? bz_in[i] : 0.f;
    const float bi  = (tid < 256) ? b_in[i]  : 0.f;
    float z_r = 0.f, h_r = 0.f;
    __syncthreads();   // staging done

    // ---- waves 4-7 persistent: rank rr, czb, rzb ----
    int rr = 0;
    float czb = 0.f, rzb = 0.f, hp = 0.f;
    if (g >= 4) {
        rr = ((g - 4) << 1) | half;
        float cz = 0.f;
        #pragma unroll
        for (int m = 0; m < 8; ++m) {
            const int k = l32 + 32 * m;
            cz = fmaf(bz_in[k], (float)wzo16[rr][k], cz);
        }
        #pragma unroll
        for (int off = 16; off >= 1; off >>= 1) cz += __shfl_xor(cz, off);
        const float bzo_r = bz_out[rr];
        czb = cz + bzo_r;
        rzb = bzo_r;
    }

    // t=0 inputs
    if (tid < 64) {
        const size_t base = (size_t)b * 32;
        sclh[tid] = (f16)((l < 32) ? s[base + l] : c[base + l - 32]);
    }
    __syncthreads();   // A0

    for (int t = 0; t < T_STEPS; ++t) {
        // ================= A..B =================
        float pfn = 0.f;
        if (tid < 64 && t + 1 < T_STEPS) {  // prefetch next inputs
            const size_t base = ((size_t)(t + 1) * BATCH + b) * 32;
            pfn = (l < 32) ? s[base + l] : c[base + l - 32];
        }

        // hp = tanh(h_{t-1}) @ V[:,rr]  (waves 4-7, dot2 on f16 pairs)
        if (g >= 4) {
            hp = 0.f;
            const h2* tp = (const h2*)thh;
            const h2* vp = (const h2*)&vt16[rr][0];
            #pragma unroll
            for (int m = 0; m < 4; ++m) {
                const int p = l32 + 32 * m;
                hp = dot2(tp[p], vp[p], hp);
            }
            #pragma unroll
            for (int off = 16; off >= 1; off >>= 1) hp += __shfl_xor(hp, off);
        }

        // out(t-1): 16 y-groups of 32 lanes (dot2 on f16 pairs)
        if (t > 0) {
            const int y = (g << 1) | half;
            float o = 0.f;
            const h2* tp = (const h2*)thh;
            const h2* wp = (const h2*)&wo16[y][0];
            #pragma unroll
            for (int m = 0; m < 4; ++m) {
                const int p = l32 + 32 * m;
                o = dot2(tp[p], wp[p], o);
            }
            #pragma unroll
            for (int off = 16; off >= 1; off >>= 1) o += __shfl_xor(o, off);
            if (l32 == 0) out[((size_t)(t - 1) * BATCH + b) * 16 + y] = o + bo[y];
        }

        // dot2 partials: W_zz K-half + Wz_in + W_in (uniform LDS broadcasts)
        {
            float az = 0.f, ah = 0.f;
            const uint4* tz = (const uint4*)&tzh[q2 << 7];
            #pragma unroll
            for (int m = 0; m < 16; ++m) {
                const uint4 u = tz[m];
                az = dot2(wzzp[4 * m + 0], bc(u.x), az);
                az = dot2(wzzp[4 * m + 1], bc(u.y), az);
                az = dot2(wzzp[4 * m + 2], bc(u.z), az);
                az = dot2(wzzp[4 * m + 3], bc(u.w), az);
            }
            const uint4* sp = (const uint4*)&sclh[q2 << 5];
            #pragma unroll
            for (int m = 0; m < 4; ++m) {
                const uint4 u = sp[m];
                az = dot2(wzip[4 * m + 0], bc(u.x), az);
                az = dot2(wzip[4 * m + 1], bc(u.y), az);
                az = dot2(wzip[4 * m + 2], bc(u.z), az);
                az = dot2(wzip[4 * m + 3], bc(u.w), az);
            }
            const uint4* wp = (const uint4*)&sclh[q2 << 4];
            #pragma unroll
            for (int m = 0; m < 2; ++m) {
                const uint4 u = wp[m];
                ah = dot2(wip[4 * m + 0], bc(u.x), ah);
                ah = dot2(wip[4 * m + 1], bc(u.y), ah);
                ah = dot2(wip[4 * m + 2], bc(u.z), ah);
                ah = dot2(wip[4 * m + 3], bc(u.w), ah);
            }
            redz[q2][i] = az;
            redh[q2][i] = ah;
        }
        __syncthreads();  // B

        // ================= B..C =================
        if (tid < 256) {
            const float tmp = redz[0][i] + redz[1][i] + bzi;
            z_r = 0.99f * z_r + 0.01f * tmp;
            tzh[i] = (f16)fast_tanh(z_r);
            states[((size_t)t * BATCH + b) * 512 + i] = z_r;
        } else {
            float zp = 0.f;
            #pragma unroll
            for (int m = 0; m < 8; ++m) {
                const int k = l32 + 32 * m;
                zp = fmaf(redz[0][k] + redz[1][k], (float)wzo16[rr][k], zp);
            }
            #pragma unroll
            for (int off = 16; off >= 1; off >>= 1) zp += __shfl_xor(zp, off);
            rzb = 0.99f * rzb + 0.01f * (zp + czb);
            const float sg = 1.0f / (1.0f + __expf(-rzb));
            if (l32 == 0) gl[rr] = sg * hp;
        }
        __syncthreads();  // C

        // ================= C..A' =================
        if (tid < 256) {
            float tmp = redh[0][i] + redh[1][i] + bi;
            #pragma unroll
            for (int r = 0; r < RANK; ++r)
                tmp = fmaf((float)ut16[r][i], gl[r], tmp);
            h_r = 0.9f * h_r + 0.1f * tmp;
            thh[i] = (f16)fast_tanh(h_r);
            states[((size_t)t * BATCH + b) * 512 + 256 + i] = h_r;
        }
        if (tid < 64 && t + 1 < T_STEPS) sclh[tid] = (f16)pfn;
        __syncthreads();  // A
    }

    // ---- final out (t = T_STEPS-1) ----
    {
        const int y = (g << 1) | half;
        float o = 0.f;
        const h2* tp = (const h2*)thh;
        const h2* wp = (const h2*)&wo16[y][0];
        #pragma unroll
        for (int m = 0; m < 4; ++m) {
            const int p = l32 + 32 * m;
            o = dot2(tp[p], wp[p], o);
        }
        #pragma unroll
        for (int off = 16; off >= 1; off >>= 1) o += __shfl_xor(o, off);
        if (l32 == 0) out[((size_t)(T_STEPS - 1) * BATCH + b) * 16 + y] = o + bo[y];
    }
}

extern "C" void kernel_launch(void* const* d_in, const int* in_sizes, int n_in,
                              void* d_out, int out_size, void* d_ws, size_t ws_size,
                              hipStream_t stream) {
    const float* s     = (const float*)d_in[0];
    const float* c     = (const float*)d_in[1];
    const float* W_zz  = (const float*)d_in[2];
    const float* Wz_in = (const float*)d_in[3];
    const float* bz_in = (const float*)d_in[4];
    const float* Wz_out= (const float*)d_in[5];
    const float* bz_out= (const float*)d_in[6];
    const float* U     = (const float*)d_in[7];
    const float* V     = (const float*)d_in[8];
    const float* W_in  = (const float*)d_in[9];
    const float* b_in  = (const float*)d_in[10];
    const float* W_out = (const float*)d_in[11];
    const float* b_out = (const float*)d_in[12];

    float* out    = (float*)d_out;
    float* states = out + (size_t)T_STEPS * BATCH * DY;

    hipLaunchKernelGGL(nmrnn_kernel, dim3(BATCH), dim3(512), 0, stream,
                       s, c, W_zz, Wz_in, bz_in, Wz_out, bz_out, U, V,
                       W_in, b_in, W_out, b_out, out, states);
}

// Round 10
// 3485.154 us; speedup vs baseline: 1.0389x; 1.0389x over previous
//
#include <hip/hip_runtime.h>
#include <math.h>

#define T_STEPS 1024
#define BATCH   512
#define DZ      256
#define DH      256
#define RANK    8
#define DY      16

// 512 blocks x 512 threads (8 waves), 1 batch element/block.
// 3-barrier structure (validated, absmax 0.0039):
//   A -> {dot2 partials, out(t-1), tanh(h)@V} -> B
//     -> {z-update (waves 0-3) || rz/sig/gl (waves 4-7)} -> C
//     -> {h-update, input publish} -> A
//
// OCCUPANCY LAW (R1-R9 tabulation): __launch_bounds__(T, N) drives BOTH
//   VGPR budget = 256/N   (R5 N=8->32, R7 N=4->64, R8 N=2->128)
//   runtime residency cap = N waves/EU  (R5->95% occ, R7->42%, R8/R9->24.4%)
// so one knob can't give budget>=112 AND 2 blocks/CU. Split them with
// amdgpu_waves_per_eu(min,max): min=2 -> budget 128 (R3's (4,4)->64
// confirms budget=256/min); max=8 -> residency uncapped by the attribute
// (VGPRs then allow 4 waves/EU = 16 waves/CU = 2 blocks co-resident).
//
// ILP: phase-A accumulator was one 80-deep serial dot2 chain (~400cyc
// dependent latency = the per-step critical path; VALUBusy 30%). Split into
// 4 independent chains (az0..az3), ah/zp/U-dot into 2.

typedef _Float16 f16;
typedef _Float16 h2 __attribute__((ext_vector_type(2)));

__device__ __forceinline__ h2 pack2(float a, float b) {
    h2 r; r.x = (f16)a; r.y = (f16)b; return r;
}
__device__ __forceinline__ h2 bc(unsigned u) { return __builtin_bit_cast(h2, u); }

__device__ __forceinline__ float dot2(h2 a, h2 b, float c) {
#if __has_builtin(__builtin_amdgcn_fdot2)
    return __builtin_amdgcn_fdot2(a, b, c, false);
#else
    return fmaf((float)a.x, (float)b.x, fmaf((float)a.y, (float)b.y, c));
#endif
}

__device__ __forceinline__ float fast_tanh(float x) {
    const float e = __expf(2.0f * x);
    return 1.0f - 2.0f / (e + 1.0f);
}

__global__ __launch_bounds__(512)
__attribute__((amdgpu_waves_per_eu(2, 8)))
void nmrnn_kernel(
    const float* __restrict__ s, const float* __restrict__ c,
    const float* __restrict__ W_zz, const float* __restrict__ Wz_in,
    const float* __restrict__ bz_in, const float* __restrict__ Wz_out,
    const float* __restrict__ bz_out, const float* __restrict__ U,
    const float* __restrict__ V, const float* __restrict__ W_in,
    const float* __restrict__ b_in, const float* __restrict__ W_out,
    const float* __restrict__ b_out,
    float* __restrict__ out, float* __restrict__ states)
{
    __shared__ __align__(16) f16 tzh[DZ];        // tanh(z) f16
    __shared__ __align__(16) f16 thh[DH];        // tanh(h) f16
    __shared__ __align__(16) f16 sclh[64];       // [s_t|c_t] f16
    __shared__ __align__(16) float redz[2][DZ];  // z-dot partials
    __shared__ __align__(16) float redh[2][DZ];  // W_in-dot partials
    __shared__ __align__(16) f16 wzo16[RANK][DZ];// Wz_out f16
    __shared__ __align__(16) f16 vt16[RANK][DH]; // V^T f16
    __shared__ __align__(16) f16 ut16[RANK][DH]; // U^T f16
    __shared__ __align__(16) f16 wo16[DY][DH];   // W_out f16
    __shared__ float gl[RANK];
    __shared__ float bo[DY];
    // total ~25.3 KB -> two blocks fit any reasonable pool

    const int tid  = threadIdx.x;
    const int i    = tid & 255;
    const int q2   = tid >> 8;     // 0..1  K-half
    const int g    = tid >> 6;     // 0..7  wave
    const int l    = tid & 63;
    const int half = l >> 5;
    const int l32  = l & 31;
    const int b    = blockIdx.x;

    // ---- persistent f16-packed weights (88 VGPRs) ----
    h2 wzzp[64];
    #pragma unroll
    for (int m = 0; m < 32; ++m) {
        const float4 v4 = *(const float4*)&W_zz[i * 256 + (q2 << 7) + (m << 2)];
        wzzp[2 * m]     = pack2(v4.x, v4.y);
        wzzp[2 * m + 1] = pack2(v4.z, v4.w);
    }
    h2 wzip[16];
    #pragma unroll
    for (int m = 0; m < 8; ++m) {
        const float4 v4 = *(const float4*)&Wz_in[i * 64 + (q2 << 5) + (m << 2)];
        wzip[2 * m]     = pack2(v4.x, v4.y);
        wzip[2 * m + 1] = pack2(v4.z, v4.w);
    }
    h2 wip[8];
    #pragma unroll
    for (int m = 0; m < 4; ++m) {
        const float4 v4 = *(const float4*)&W_in[i * 32 + (q2 << 4) + (m << 2)];
        wip[2 * m]     = pack2(v4.x, v4.y);
        wip[2 * m + 1] = pack2(v4.z, v4.w);
    }

    // ---- stage small matrices as f16 ----
    {   // Wz_out: 2048 floats -> wzo16
        const int idx = tid * 4;
        const float4 v4 = *(const float4*)&Wz_out[idx];
        h2* dst = (h2*)&((f16*)wzo16)[idx];
        dst[0] = pack2(v4.x, v4.y);
        dst[1] = pack2(v4.z, v4.w);
    }
    #pragma unroll
    for (int it = 0; it < 2; ++it) {  // W_out: 4096 floats -> wo16
        const int idx = tid * 4 + it * 2048;
        const float4 v4 = *(const float4*)&W_out[idx];
        h2* dst = (h2*)&((f16*)wo16)[idx];
        dst[0] = pack2(v4.x, v4.y);
        dst[1] = pack2(v4.z, v4.w);
    }
    if (tid < 256) {  // transpose V, U -> f16
        #pragma unroll
        for (int r = 0; r < RANK; ++r) vt16[r][tid] = (f16)V[tid * RANK + r];
        #pragma unroll
        for (int r = 0; r < RANK; ++r) ut16[r][tid] = (f16)U[tid * RANK + r];
        tzh[tid] = (f16)0.f; thh[tid] = (f16)0.f;
    }
    if (tid < DY) bo[tid] = b_out[tid];

    const float bzi = (tid < 256) ? bz_in[i] : 0.f;
    const float bi  = (tid < 256) ? b_in[i]  : 0.f;
    float z_r = 0.f, h_r = 0.f;
    __syncthreads();   // staging done

    // ---- waves 4-7 persistent: rank rr, czb, rzb ----
    int rr = 0;
    float czb = 0.f, rzb = 0.f, hp = 0.f;
    if (g >= 4) {
        rr = ((g - 4) << 1) | half;
        float cz = 0.f;
        #pragma unroll
        for (int m = 0; m < 8; ++m) {
            const int k = l32 + 32 * m;
            cz = fmaf(bz_in[k], (float)wzo16[rr][k], cz);
        }
        #pragma unroll
        for (int off = 16; off >= 1; off >>= 1) cz += __shfl_xor(cz, off);
        const float bzo_r = bz_out[rr];
        czb = cz + bzo_r;
        rzb = bzo_r;
    }

    // t=0 inputs
    if (tid < 64) {
        const size_t base = (size_t)b * 32;
        sclh[tid] = (f16)((l < 32) ? s[base + l] : c[base + l - 32]);
    }
    __syncthreads();   // A0

    for (int t = 0; t < T_STEPS; ++t) {
        // ================= A..B =================
        float pfn = 0.f;
        if (tid < 64 && t + 1 < T_STEPS) {  // prefetch next inputs
            const size_t base = ((size_t)(t + 1) * BATCH + b) * 32;
            pfn = (l < 32) ? s[base + l] : c[base + l - 32];
        }

        // hp = tanh(h_{t-1}) @ V[:,rr]  (waves 4-7, 2 chains)
        if (g >= 4) {
            const h2* tp = (const h2*)thh;
            const h2* vp = (const h2*)&vt16[rr][0];
            float h0 = 0.f, h1 = 0.f;
            h0 = dot2(tp[l32],      vp[l32],      h0);
            h1 = dot2(tp[l32 + 32], vp[l32 + 32], h1);
            h0 = dot2(tp[l32 + 64], vp[l32 + 64], h0);
            h1 = dot2(tp[l32 + 96], vp[l32 + 96], h1);
            hp = h0 + h1;
            #pragma unroll
            for (int off = 16; off >= 1; off >>= 1) hp += __shfl_xor(hp, off);
        }

        // out(t-1): 16 y-groups of 32 lanes (2 chains)
        if (t > 0) {
            const int y = (g << 1) | half;
            const h2* tp = (const h2*)thh;
            const h2* wp = (const h2*)&wo16[y][0];
            float o0 = 0.f, o1 = 0.f;
            o0 = dot2(tp[l32],      wp[l32],      o0);
            o1 = dot2(tp[l32 + 32], wp[l32 + 32], o1);
            o0 = dot2(tp[l32 + 64], wp[l32 + 64], o0);
            o1 = dot2(tp[l32 + 96], wp[l32 + 96], o1);
            float o = o0 + o1;
            #pragma unroll
            for (int off = 16; off >= 1; off >>= 1) o += __shfl_xor(o, off);
            if (l32 == 0) out[((size_t)(t - 1) * BATCH + b) * 16 + y] = o + bo[y];
        }

        // dot2 partials: W_zz K-half + Wz_in + W_in. 4 independent chains.
        {
            float az0 = 0.f, az1 = 0.f, az2 = 0.f, az3 = 0.f;
            float ah0 = 0.f, ah1 = 0.f;
            const uint4* tz = (const uint4*)&tzh[q2 << 7];
            #pragma unroll
            for (int m = 0; m < 16; ++m) {
                const uint4 u = tz[m];
                az0 = dot2(wzzp[4 * m + 0], bc(u.x), az0);
                az1 = dot2(wzzp[4 * m + 1], bc(u.y), az1);
                az2 = dot2(wzzp[4 * m + 2], bc(u.z), az2);
                az3 = dot2(wzzp[4 * m + 3], bc(u.w), az3);
            }
            const uint4* sp = (const uint4*)&sclh[q2 << 5];
            #pragma unroll
            for (int m = 0; m < 4; ++m) {
                const uint4 u = sp[m];
                az0 = dot2(wzip[4 * m + 0], bc(u.x), az0);
                az1 = dot2(wzip[4 * m + 1], bc(u.y), az1);
                az2 = dot2(wzip[4 * m + 2], bc(u.z), az2);
                az3 = dot2(wzip[4 * m + 3], bc(u.w), az3);
            }
            const uint4* wp = (const uint4*)&sclh[q2 << 4];
            #pragma unroll
            for (int m = 0; m < 2; ++m) {
                const uint4 u = wp[m];
                ah0 = dot2(wip[4 * m + 0], bc(u.x), ah0);
                ah1 = dot2(wip[4 * m + 1], bc(u.y), ah1);
                ah0 = dot2(wip[4 * m + 2], bc(u.z), ah0);
                ah1 = dot2(wip[4 * m + 3], bc(u.w), ah1);
            }
            redz[q2][i] = (az0 + az1) + (az2 + az3);
            redh[q2][i] = ah0 + ah1;
        }
        __syncthreads();  // B

        // ================= B..C =================
        if (tid < 256) {
            const float tmp = redz[0][i] + redz[1][i] + bzi;
            z_r = 0.99f * z_r + 0.01f * tmp;
            tzh[i] = (f16)fast_tanh(z_r);
            states[((size_t)t * BATCH + b) * 512 + i] = z_r;
        } else {
            float zp0 = 0.f, zp1 = 0.f;
            #pragma unroll
            for (int m = 0; m < 4; ++m) {
                const int k0 = l32 + 64 * m;
                const int k1 = k0 + 32;
                zp0 = fmaf(redz[0][k0] + redz[1][k0], (float)wzo16[rr][k0], zp0);
                zp1 = fmaf(redz[0][k1] + redz[1][k1], (float)wzo16[rr][k1], zp1);
            }
            float zp = zp0 + zp1;
            #pragma unroll
            for (int off = 16; off >= 1; off >>= 1) zp += __shfl_xor(zp, off);
            rzb = 0.99f * rzb + 0.01f * (zp + czb);
            const float sg = 1.0f / (1.0f + __expf(-rzb));
            if (l32 == 0) gl[rr] = sg * hp;
        }
        __syncthreads();  // C

        // ================= C..A' =================
        if (tid < 256) {
            float t0 = redh[0][i] + redh[1][i] + bi, t1 = 0.f;
            #pragma unroll
            for (int r = 0; r < 4; ++r) {
                t0 = fmaf((float)ut16[2 * r][i],     gl[2 * r],     t0);
                t1 = fmaf((float)ut16[2 * r + 1][i], gl[2 * r + 1], t1);
            }
            h_r = 0.9f * h_r + 0.1f * (t0 + t1);
            thh[i] = (f16)fast_tanh(h_r);
            states[((size_t)t * BATCH + b) * 512 + 256 + i] = h_r;
        }
        if (tid < 64 && t + 1 < T_STEPS) sclh[tid] = (f16)pfn;
        __syncthreads();  // A
    }

    // ---- final out (t = T_STEPS-1) ----
    {
        const int y = (g << 1) | half;
        const h2* tp = (const h2*)thh;
        const h2* wp = (const h2*)&wo16[y][0];
        float o0 = 0.f, o1 = 0.f;
        o0 = dot2(tp[l32],      wp[l32],      o0);
        o1 = dot2(tp[l32 + 32], wp[l32 + 32], o1);
        o0 = dot2(tp[l32 + 64], wp[l32 + 64], o0);
        o1 = dot2(tp[l32 + 96], wp[l32 + 96], o1);
        float o = o0 + o1;
        #pragma unroll
        for (int off = 16; off >= 1; off >>= 1) o += __shfl_xor(o, off);
        if (l32 == 0) out[((size_t)(T_STEPS - 1) * BATCH + b) * 16 + y] = o + bo[y];
    }
}

extern "C" void kernel_launch(void* const* d_in, const int* in_sizes, int n_in,
                              void* d_out, int out_size, void* d_ws, size_t ws_size,
                              hipStream_t stream) {
    const float* s     = (const float*)d_in[0];
    const float* c     = (const float*)d_in[1];
    const float* W_zz  = (const float*)d_in[2];
    const float* Wz_in = (const float*)d_in[3];
    const float* bz_in = (const float*)d_in[4];
    const float* Wz_out= (const float*)d_in[5];
    const float* bz_out= (const float*)d_in[6];
    const float* U     = (const float*)d_in[7];
    const float* V     = (const float*)d_in[8];
    const float* W_in  = (const float*)d_in[9];
    const float* b_in  = (const float*)d_in[10];
    const float* W_out = (const float*)d_in[11];
    const float* b_out = (const float*)d_in[12];

    float* out    = (float*)d_out;
    float* states = out + (size_t)T_STEPS * BATCH * DY;

    hipLaunchKernelGGL(nmrnn_kernel, dim3(BATCH), dim3(512), 0, stream,
                       s, c, W_zz, Wz_in, bz_in, Wz_out, bz_out, U, V,
                       W_in, b_in, W_out, b_out, out, states);
}

// Round 11
// 2840.970 us; speedup vs baseline: 1.2745x; 1.2267x over previous
//
#include <hip/hip_runtime.h>
#include <math.h>

#define T_STEPS 1024
#define BATCH   512
#define DZ      256
#define DH      256
#define RANK    8
#define DY      16

// 256 blocks x 1024 threads (16 waves), TWO batch elements per block ->
// exactly 1 block/CU on 256 CUs: single pass, no co-residency needed.
// (R8-R10: 512-block 8-wave kernels ran as 2 sequential passes, occupancy
// pinned at 24.4% regardless of LDS size or waves_per_eu hints.)
//
// 3-barrier structure per step (validated through R10, absmax 0.0039):
//   A -> {dot2 partials (both batches), out(t-1), tanh(h)@V} -> B
//     -> {z-update (tid<512) || rz/sig/gl (waves 8-15)} -> C
//     -> {h-update, input publish} -> A
//
// Resource shape = R4's verified no-spill config: __launch_bounds__(1024,4)
// -> 64-VGPR budget; thread (i=tid&255, q=tid>>8) holds f16-packed
// W_zz[i,64q..+64] (32 h2) + Wz_in[i,16q..+16] (8) + W_in[i,8q..+8] (4)
// = 44 persistent regs. Incremental rz (z@Wz_out maintained recursively)
// kills the z->signal->h barrier chain.

typedef _Float16 f16;
typedef _Float16 h2 __attribute__((ext_vector_type(2)));

__device__ __forceinline__ h2 pack2(float a, float b) {
    h2 r; r.x = (f16)a; r.y = (f16)b; return r;
}
__device__ __forceinline__ h2 bc(unsigned u) { return __builtin_bit_cast(h2, u); }

__device__ __forceinline__ float dot2(h2 a, h2 b, float c) {
#if __has_builtin(__builtin_amdgcn_fdot2)
    return __builtin_amdgcn_fdot2(a, b, c, false);
#else
    return fmaf((float)a.x, (float)b.x, fmaf((float)a.y, (float)b.y, c));
#endif
}

__device__ __forceinline__ float fast_tanh(float x) {
    const float e = __expf(2.0f * x);
    return 1.0f - 2.0f / (e + 1.0f);
}

__global__ __launch_bounds__(1024, 4)
void nmrnn_kernel(
    const float* __restrict__ s, const float* __restrict__ c,
    const float* __restrict__ W_zz, const float* __restrict__ Wz_in,
    const float* __restrict__ bz_in, const float* __restrict__ Wz_out,
    const float* __restrict__ bz_out, const float* __restrict__ U,
    const float* __restrict__ V, const float* __restrict__ W_in,
    const float* __restrict__ b_in, const float* __restrict__ W_out,
    const float* __restrict__ b_out,
    float* __restrict__ out, float* __restrict__ states)
{
    __shared__ __align__(16) f16 tzh[2][DZ];       // tanh(z) f16, per batch
    __shared__ __align__(16) f16 thh[2][DH];       // tanh(h) f16
    __shared__ __align__(16) f16 sclh[2][64];      // [s_t|c_t] f16
    __shared__ __align__(16) float redz[4][2][DZ]; // z-dot partials [q][b][i]
    __shared__ __align__(16) float redh[4][2][DZ]; // W_in partials
    __shared__ __align__(16) f16 wzo16[RANK][DZ];  // Wz_out f16
    __shared__ __align__(16) f16 vt16[RANK][DH];   // V^T f16
    __shared__ __align__(16) f16 ut16[RANK][DH];   // U^T f16
    __shared__ __align__(16) f16 wo16[DY][DH];     // W_out f16
    __shared__ float gl[2][RANK];
    __shared__ float bo[DY];
    // ~39 KB

    const int tid = threadIdx.x;
    const int i   = tid & 255;
    const int q   = tid >> 8;        // 0..3  K-quadrant
    const int w   = tid >> 6;        // 0..15 wave
    const int l32 = tid & 31;
    const int b0  = blockIdx.x * 2;

    // out groups (all threads): 32 groups of 32 lanes
    const int g2 = tid >> 5;
    const int oy = g2 & 15;          // y index
    const int ob = g2 >> 4;          // batch index
    // rz groups (waves 8-15): 16 groups of 32 lanes
    const int gg = (tid >> 5) & 15;
    const int rr = gg & 7;           // rank
    const int rb = gg >> 3;          // batch

    // ---- persistent f16-packed weights (44 VGPRs) ----
    h2 wzzp[32];
    #pragma unroll
    for (int m = 0; m < 16; ++m) {
        const float4 v4 = *(const float4*)&W_zz[i * 256 + (q << 6) + (m << 2)];
        wzzp[2 * m]     = pack2(v4.x, v4.y);
        wzzp[2 * m + 1] = pack2(v4.z, v4.w);
    }
    h2 wzip[8];
    #pragma unroll
    for (int m = 0; m < 4; ++m) {
        const float4 v4 = *(const float4*)&Wz_in[i * 64 + (q << 4) + (m << 2)];
        wzip[2 * m]     = pack2(v4.x, v4.y);
        wzip[2 * m + 1] = pack2(v4.z, v4.w);
    }
    h2 wip[4];
    #pragma unroll
    for (int m = 0; m < 2; ++m) {
        const float4 v4 = *(const float4*)&W_in[i * 32 + (q << 3) + (m << 2)];
        wip[2 * m]     = pack2(v4.x, v4.y);
        wip[2 * m + 1] = pack2(v4.z, v4.w);
    }

    // ---- stage small matrices as f16 ----
    if (tid < 512) {  // Wz_out: 2048 floats
        const int idx = tid * 4;
        const float4 v4 = *(const float4*)&Wz_out[idx];
        h2* dst = (h2*)&((f16*)wzo16)[idx];
        dst[0] = pack2(v4.x, v4.y);
        dst[1] = pack2(v4.z, v4.w);
    }
    {   // W_out: 4096 floats
        const int idx = tid * 4;
        const float4 v4 = *(const float4*)&W_out[idx];
        h2* dst = (h2*)&((f16*)wo16)[idx];
        dst[0] = pack2(v4.x, v4.y);
        dst[1] = pack2(v4.z, v4.w);
    }
    if (tid < 256) {  // transpose V, U -> f16
        #pragma unroll
        for (int r = 0; r < RANK; ++r) vt16[r][tid] = (f16)V[tid * RANK + r];
        #pragma unroll
        for (int r = 0; r < RANK; ++r) ut16[r][tid] = (f16)U[tid * RANK + r];
    }
    if (tid < 512) { tzh[tid >> 8][i] = (f16)0.f; thh[tid >> 8][i] = (f16)0.f; }
    if (tid < DY) bo[tid] = b_out[tid];
    if (tid < 128) {  // t=0 inputs
        const int bb = tid >> 6, r = tid & 63;
        const size_t base = (size_t)(b0 + bb) * 32;
        sclh[bb][r] = (f16)((r < 32) ? s[base + r] : c[base + r - 32]);
    }

    const float bzi = (tid < 512) ? bz_in[i] : 0.f;
    const float bi  = (tid < 512) ? b_in[i]  : 0.f;
    float z_r = 0.f, h_r = 0.f;
    __syncthreads();   // staging done (wzo16 needed below)

    // ---- waves 8-15 persistent: czb (rank const), rzb (recurrent) ----
    float czb = 0.f, rzb = 0.f, hp = 0.f;
    if (w >= 8) {
        float cz = 0.f;
        #pragma unroll
        for (int m = 0; m < 8; ++m) {
            const int k = l32 + 32 * m;
            cz = fmaf(bz_in[k], (float)wzo16[rr][k], cz);
        }
        #pragma unroll
        for (int off = 16; off >= 1; off >>= 1) cz += __shfl_xor(cz, off);
        const float bzo_r = bz_out[rr];
        czb = cz + bzo_r;
        rzb = bzo_r;
    }
    __syncthreads();   // A0

    for (int t = 0; t < T_STEPS; ++t) {
        // ================= A..B =================
        float pfn = 0.f;
        if (tid < 128 && t + 1 < T_STEPS) {  // prefetch next inputs
            const int bb = tid >> 6, r = tid & 63;
            const size_t base = ((size_t)(t + 1) * BATCH + b0 + bb) * 32;
            pfn = (r < 32) ? s[base + r] : c[base + r - 32];
        }

        // hp = tanh(h_{t-1}) @ V[:,rr] for batch rb (waves 8-15, 2 chains)
        if (w >= 8) {
            const h2* tp = (const h2*)&thh[rb][0];
            const h2* vp = (const h2*)&vt16[rr][0];
            float h0 = 0.f, h1 = 0.f;
            h0 = dot2(tp[l32],      vp[l32],      h0);
            h1 = dot2(tp[l32 + 32], vp[l32 + 32], h1);
            h0 = dot2(tp[l32 + 64], vp[l32 + 64], h0);
            h1 = dot2(tp[l32 + 96], vp[l32 + 96], h1);
            hp = h0 + h1;
            #pragma unroll
            for (int off = 16; off >= 1; off >>= 1) hp += __shfl_xor(hp, off);
        }

        // out(t-1): 32 groups (y, batch) of 32 lanes
        if (t > 0) {
            const h2* tp = (const h2*)&thh[ob][0];
            const h2* wp = (const h2*)&wo16[oy][0];
            float o0 = 0.f, o1 = 0.f;
            o0 = dot2(tp[l32],      wp[l32],      o0);
            o1 = dot2(tp[l32 + 32], wp[l32 + 32], o1);
            o0 = dot2(tp[l32 + 64], wp[l32 + 64], o0);
            o1 = dot2(tp[l32 + 96], wp[l32 + 96], o1);
            float o = o0 + o1;
            #pragma unroll
            for (int off = 16; off >= 1; off >>= 1) o += __shfl_xor(o, off);
            if (l32 == 0) out[((size_t)(t - 1) * BATCH + b0 + ob) * 16 + oy] = o + bo[oy];
        }

        // dot2 partials for BOTH batches (q-quadrant of K), 4 indep chains
        {
            float az0 = 0.f, az1 = 0.f, ah0 = 0.f, ah1 = 0.f;
            const uint4* tz0 = (const uint4*)&tzh[0][q << 6];
            const uint4* tz1 = (const uint4*)&tzh[1][q << 6];
            #pragma unroll
            for (int m = 0; m < 8; ++m) {
                const uint4 u0 = tz0[m];
                const uint4 u1 = tz1[m];
                az0 = dot2(wzzp[4 * m + 0], bc(u0.x), az0);
                az0 = dot2(wzzp[4 * m + 1], bc(u0.y), az0);
                az0 = dot2(wzzp[4 * m + 2], bc(u0.z), az0);
                az0 = dot2(wzzp[4 * m + 3], bc(u0.w), az0);
                az1 = dot2(wzzp[4 * m + 0], bc(u1.x), az1);
                az1 = dot2(wzzp[4 * m + 1], bc(u1.y), az1);
                az1 = dot2(wzzp[4 * m + 2], bc(u1.z), az1);
                az1 = dot2(wzzp[4 * m + 3], bc(u1.w), az1);
            }
            const uint4* sp0 = (const uint4*)&sclh[0][q << 4];
            const uint4* sp1 = (const uint4*)&sclh[1][q << 4];
            #pragma unroll
            for (int m = 0; m < 2; ++m) {
                const uint4 u0 = sp0[m];
                const uint4 u1 = sp1[m];
                az0 = dot2(wzip[4 * m + 0], bc(u0.x), az0);
                az0 = dot2(wzip[4 * m + 1], bc(u0.y), az0);
                az0 = dot2(wzip[4 * m + 2], bc(u0.z), az0);
                az0 = dot2(wzip[4 * m + 3], bc(u0.w), az0);
                az1 = dot2(wzip[4 * m + 0], bc(u1.x), az1);
                az1 = dot2(wzip[4 * m + 1], bc(u1.y), az1);
                az1 = dot2(wzip[4 * m + 2], bc(u1.z), az1);
                az1 = dot2(wzip[4 * m + 3], bc(u1.w), az1);
            }
            const uint4 uw0 = *(const uint4*)&sclh[0][q << 3];
            const uint4 uw1 = *(const uint4*)&sclh[1][q << 3];
            ah0 = dot2(wip[0], bc(uw0.x), ah0);
            ah0 = dot2(wip[1], bc(uw0.y), ah0);
            ah0 = dot2(wip[2], bc(uw0.z), ah0);
            ah0 = dot2(wip[3], bc(uw0.w), ah0);
            ah1 = dot2(wip[0], bc(uw1.x), ah1);
            ah1 = dot2(wip[1], bc(uw1.y), ah1);
            ah1 = dot2(wip[2], bc(uw1.z), ah1);
            ah1 = dot2(wip[3], bc(uw1.w), ah1);
            redz[q][0][i] = az0;
            redz[q][1][i] = az1;
            redh[q][0][i] = ah0;
            redh[q][1][i] = ah1;
        }
        __syncthreads();  // B

        // ================= B..C =================
        if (tid < 512) {
            const int bb = tid >> 8;
            const float tmp = redz[0][bb][i] + redz[1][bb][i]
                            + redz[2][bb][i] + redz[3][bb][i] + bzi;
            z_r = 0.99f * z_r + 0.01f * tmp;
            tzh[bb][i] = (f16)fast_tanh(z_r);
            states[((size_t)t * BATCH + b0 + bb) * 512 + i] = z_r;
        } else {
            float zp0 = 0.f, zp1 = 0.f;
            #pragma unroll
            for (int m = 0; m < 4; ++m) {
                const int k0 = l32 + 64 * m;
                const int k1 = k0 + 32;
                const float rs0 = redz[0][rb][k0] + redz[1][rb][k0]
                                + redz[2][rb][k0] + redz[3][rb][k0];
                const float rs1 = redz[0][rb][k1] + redz[1][rb][k1]
                                + redz[2][rb][k1] + redz[3][rb][k1];
                zp0 = fmaf(rs0, (float)wzo16[rr][k0], zp0);
                zp1 = fmaf(rs1, (float)wzo16[rr][k1], zp1);
            }
            float zp = zp0 + zp1;
            #pragma unroll
            for (int off = 16; off >= 1; off >>= 1) zp += __shfl_xor(zp, off);
            rzb = 0.99f * rzb + 0.01f * (zp + czb);
            const float sg = 1.0f / (1.0f + __expf(-rzb));
            if (l32 == 0) gl[rb][rr] = sg * hp;
        }
        __syncthreads();  // C

        // ================= C..A' =================
        if (tid < 512) {
            const int bb = tid >> 8;
            float t0 = redh[0][bb][i] + redh[1][bb][i]
                     + redh[2][bb][i] + redh[3][bb][i] + bi;
            float t1 = 0.f;
            #pragma unroll
            for (int r = 0; r < 4; ++r) {
                t0 = fmaf((float)ut16[2 * r][i],     gl[bb][2 * r],     t0);
                t1 = fmaf((float)ut16[2 * r + 1][i], gl[bb][2 * r + 1], t1);
            }
            h_r = 0.9f * h_r + 0.1f * (t0 + t1);
            thh[bb][i] = (f16)fast_tanh(h_r);
            states[((size_t)t * BATCH + b0 + bb) * 512 + 256 + i] = h_r;
        }
        if (tid < 128 && t + 1 < T_STEPS)
            sclh[tid >> 6][tid & 63] = (f16)pfn;
        __syncthreads();  // A
    }

    // ---- final out (t = T_STEPS-1) ----
    {
        const h2* tp = (const h2*)&thh[ob][0];
        const h2* wp = (const h2*)&wo16[oy][0];
        float o0 = 0.f, o1 = 0.f;
        o0 = dot2(tp[l32],      wp[l32],      o0);
        o1 = dot2(tp[l32 + 32], wp[l32 + 32], o1);
        o0 = dot2(tp[l32 + 64], wp[l32 + 64], o0);
        o1 = dot2(tp[l32 + 96], wp[l32 + 96], o1);
        float o = o0 + o1;
        #pragma unroll
        for (int off = 16; off >= 1; off >>= 1) o += __shfl_xor(o, off);
        if (l32 == 0)
            out[((size_t)(T_STEPS - 1) * BATCH + b0 + ob) * 16 + oy] = o + bo[oy];
    }
}

extern "C" void kernel_launch(void* const* d_in, const int* in_sizes, int n_in,
                              void* d_out, int out_size, void* d_ws, size_t ws_size,
                              hipStream_t stream) {
    const float* s     = (const float*)d_in[0];
    const float* c     = (const float*)d_in[1];
    const float* W_zz  = (const float*)d_in[2];
    const float* Wz_in = (const float*)d_in[3];
    const float* bz_in = (const float*)d_in[4];
    const float* Wz_out= (const float*)d_in[5];
    const float* bz_out= (const float*)d_in[6];
    const float* U     = (const float*)d_in[7];
    const float* V     = (const float*)d_in[8];
    const float* W_in  = (const float*)d_in[9];
    const float* b_in  = (const float*)d_in[10];
    const float* W_out = (const float*)d_in[11];
    const float* b_out = (const float*)d_in[12];

    float* out    = (float*)d_out;
    float* states = out + (size_t)T_STEPS * BATCH * DY;

    hipLaunchKernelGGL(nmrnn_kernel, dim3(BATCH / 2), dim3(1024), 0, stream,
                       s, c, W_zz, Wz_in, bz_in, Wz_out, bz_out, U, V,
                       W_in, b_in, W_out, b_out, out, states);
}

// Round 12
// 2264.980 us; speedup vs baseline: 1.5986x; 1.2543x over previous
//
#include <hip/hip_runtime.h>
#include <math.h>

#define T_STEPS 1024
#define BATCH   512
#define DZ      256
#define DH      256
#define RANK    8
#define DY      16

// 256 blocks x 1024 threads (16 waves), 2 batch elements/block -> exactly
// 1 block/CU, single pass (R11 verified: occ 48%, VGPR 64, no spills).
//
// TWO barriers/step (was 3). Key algebra: signal projection rz = z@Wzo is
// advanced in phase A using PROJECTED weights Pz = Wzo@W_zz, Pzi = Wzo@Wz_in
// (precomputed once per block):
//   zp_t = tanh(z_{t-1})@Pz^T + scl_t@Pzi^T   (no redz dependency!)
//   rz_t = 0.99 rz_{t-1} + 0.01 (zp_t + czb); gl = sigmoid(rz)*hp
// so gl is published BEFORE barrier B, and the z-update (tid<512) and
// h-update (tid>=512, consumes gl) run in parallel in B..A'.
//   A -> {out(t-1), [hi] hp/zp/rz/gl, main dot2 partials} -> B
//     -> {z-update (lo) || h-update (hi), input publish} -> A
//
// Resource shape: R4/R11's verified no-spill config __launch_bounds__(1024,4)
// -> 64-VGPR budget; 44 persistent f16-packed weight regs per thread.

typedef _Float16 f16;
typedef _Float16 h2 __attribute__((ext_vector_type(2)));

__device__ __forceinline__ h2 pack2(float a, float b) {
    h2 r; r.x = (f16)a; r.y = (f16)b; return r;
}
__device__ __forceinline__ h2 bc(unsigned u) { return __builtin_bit_cast(h2, u); }

__device__ __forceinline__ float dot2(h2 a, h2 b, float c) {
#if __has_builtin(__builtin_amdgcn_fdot2)
    return __builtin_amdgcn_fdot2(a, b, c, false);
#else
    return fmaf((float)a.x, (float)b.x, fmaf((float)a.y, (float)b.y, c));
#endif
}

__device__ __forceinline__ float fast_tanh(float x) {
    const float e = __expf(2.0f * x);
    return 1.0f - 2.0f / (e + 1.0f);
}

__global__ __launch_bounds__(1024, 4)
void nmrnn_kernel(
    const float* __restrict__ s, const float* __restrict__ c,
    const float* __restrict__ W_zz, const float* __restrict__ Wz_in,
    const float* __restrict__ bz_in, const float* __restrict__ Wz_out,
    const float* __restrict__ bz_out, const float* __restrict__ U,
    const float* __restrict__ V, const float* __restrict__ W_in,
    const float* __restrict__ b_in, const float* __restrict__ W_out,
    const float* __restrict__ b_out,
    float* __restrict__ out, float* __restrict__ states)
{
    __shared__ __align__(16) f16 tzh[2][DZ];       // tanh(z) f16, per batch
    __shared__ __align__(16) f16 thh[2][DH];       // tanh(h) f16
    __shared__ __align__(16) f16 sclh[2][64];      // [s_t|c_t] f16
    __shared__ __align__(16) float redz[4][2][DZ]; // z-dot partials [q][b][i]
    __shared__ __align__(16) float redh[4][2][DZ]; // W_in partials
    __shared__ __align__(16) f16 pz16[RANK][DZ];   // Wzo @ W_zz (projected)
    __shared__ __align__(16) f16 pzi16[RANK][64];  // Wzo @ Wz_in
    __shared__ __align__(16) f16 vt16[RANK][DH];   // V^T f16
    __shared__ __align__(16) f16 ut16[RANK][DH];   // U^T f16
    __shared__ __align__(16) f16 wo16[DY][DH];     // W_out f16
    __shared__ float gl[2][RANK];
    __shared__ float bo[DY];
    // ~40 KB

    const int tid = threadIdx.x;
    const int i   = tid & 255;
    const int q   = tid >> 8;        // 0..3  K-quadrant
    const int l32 = tid & 31;
    const int b0  = blockIdx.x * 2;
    const bool hi = (tid >= 512);

    // out groups (all threads): 32 groups of 32 lanes
    const int g2 = tid >> 5;
    const int oy = g2 & 15;          // y index
    const int ob = g2 >> 4;          // batch index
    // gl groups (hi threads): 16 groups of 32 lanes
    const int gg = g2 & 15;
    const int rr = gg & 7;           // rank
    const int rb = gg >> 3;          // batch

    // ---- persistent f16-packed weights (44 VGPRs) ----
    h2 wzzp[32];
    #pragma unroll
    for (int m = 0; m < 16; ++m) {
        const float4 v4 = *(const float4*)&W_zz[i * 256 + (q << 6) + (m << 2)];
        wzzp[2 * m]     = pack2(v4.x, v4.y);
        wzzp[2 * m + 1] = pack2(v4.z, v4.w);
    }
    h2 wzip[8];
    #pragma unroll
    for (int m = 0; m < 4; ++m) {
        const float4 v4 = *(const float4*)&Wz_in[i * 64 + (q << 4) + (m << 2)];
        wzip[2 * m]     = pack2(v4.x, v4.y);
        wzip[2 * m + 1] = pack2(v4.z, v4.w);
    }
    h2 wip[4];
    #pragma unroll
    for (int m = 0; m < 2; ++m) {
        const float4 v4 = *(const float4*)&W_in[i * 32 + (q << 3) + (m << 2)];
        wip[2 * m]     = pack2(v4.x, v4.y);
        wip[2 * m + 1] = pack2(v4.z, v4.w);
    }

    // ---- stage small matrices as f16 ----
    {   // W_out: 4096 floats
        const int idx = tid * 4;
        const float4 v4 = *(const float4*)&W_out[idx];
        h2* dst = (h2*)&((f16*)wo16)[idx];
        dst[0] = pack2(v4.x, v4.y);
        dst[1] = pack2(v4.z, v4.w);
    }
    if (tid < 256) {  // transpose V, U -> f16
        #pragma unroll
        for (int r = 0; r < RANK; ++r) vt16[r][tid] = (f16)V[tid * RANK + r];
        #pragma unroll
        for (int r = 0; r < RANK; ++r) ut16[r][tid] = (f16)U[tid * RANK + r];
    }
    if (tid < 512) { tzh[tid >> 8][i] = (f16)0.f; thh[tid >> 8][i] = (f16)0.f; }
    if (tid < DY) bo[tid] = b_out[tid];
    if (tid < 128) {  // t=0 inputs
        const int bb = tid >> 6, r = tid & 63;
        const size_t base = (size_t)(b0 + bb) * 32;
        sclh[bb][r] = (f16)((r < 32) ? s[base + r] : c[base + r - 32]);
    }

    // ---- projected weights Pz = Wzo @ W_zz, Pzi = Wzo @ Wz_in (one-time) ----
    #pragma unroll
    for (int p = 0; p < 2; ++p) {
        const int r = q + 4 * p;                 // thread (r, j=i)
        const float* wrow = &Wz_out[r * 256];
        float a0 = 0.f, a1 = 0.f;
        #pragma unroll 4
        for (int k = 0; k < 256; k += 2) {
            a0 = fmaf(wrow[k],     W_zz[k * 256 + i],       a0);
            a1 = fmaf(wrow[k + 1], W_zz[(k + 1) * 256 + i], a1);
        }
        pz16[r][i] = (f16)(a0 + a1);
    }
    if (tid < 512) {
        const int r = tid >> 6, j = tid & 63;
        const float* wrow = &Wz_out[r * 256];
        float a0 = 0.f, a1 = 0.f;
        #pragma unroll 4
        for (int k = 0; k < 256; k += 2) {
            a0 = fmaf(wrow[k],     Wz_in[k * 64 + j],       a0);
            a1 = fmaf(wrow[k + 1], Wz_in[(k + 1) * 64 + j], a1);
        }
        pzi16[r][j] = (f16)(a0 + a1);
    }

    const float bias_r = hi ? b_in[i] : bz_in[i];
    float state_r = 0.f;   // z for lo threads, h for hi threads

    // ---- hi-thread persistent: czb (const), rzb (recurrent) ----
    float czb = 0.f, rzb = 0.f;
    if (hi) {
        float cz = 0.f;
        #pragma unroll
        for (int m = 0; m < 8; ++m) {
            const int k = l32 + 32 * m;
            cz = fmaf(bz_in[k], Wz_out[rr * 256 + k], cz);
        }
        #pragma unroll
        for (int off = 16; off >= 1; off >>= 1) cz += __shfl_xor(cz, off);
        const float bzo_r = bz_out[rr];
        czb = cz + bzo_r;
        rzb = bzo_r;
    }
    __syncthreads();   // A0: staging + projections done

    for (int t = 0; t < T_STEPS; ++t) {
        // ================= A..B =================
        float pfn = 0.f;
        if (tid < 128 && t + 1 < T_STEPS) {  // prefetch next inputs
            const int bb = tid >> 6, r = tid & 63;
            const size_t base = ((size_t)(t + 1) * BATCH + b0 + bb) * 32;
            pfn = (r < 32) ? s[base + r] : c[base + r - 32];
        }

        // out(t-1): 32 groups (y, batch) of 32 lanes
        if (t > 0) {
            const h2* tp = (const h2*)&thh[ob][0];
            const h2* wp = (const h2*)&wo16[oy][0];
            float o0 = 0.f, o1 = 0.f;
            o0 = dot2(tp[l32],      wp[l32],      o0);
            o1 = dot2(tp[l32 + 32], wp[l32 + 32], o1);
            o0 = dot2(tp[l32 + 64], wp[l32 + 64], o0);
            o1 = dot2(tp[l32 + 96], wp[l32 + 96], o1);
            float o = o0 + o1;
            #pragma unroll
            for (int off = 16; off >= 1; off >>= 1) o += __shfl_xor(o, off);
            if (l32 == 0) out[((size_t)(t - 1) * BATCH + b0 + ob) * 16 + oy] = o + bo[oy];
        }

        // hi: hp = tanh(h)@V[:,rr], zp = tanh(z)@Pz[rr] + scl@Pzi[rr]
        //     -> rzb update, sig, gl  (all pre-barrier!)
        if (hi) {
            const h2* tp  = (const h2*)&thh[rb][0];
            const h2* vp  = (const h2*)&vt16[rr][0];
            const h2* tzp = (const h2*)&tzh[rb][0];
            const h2* pzp = (const h2*)&pz16[rr][0];
            float hp0 = 0.f, hp1 = 0.f, zp0 = 0.f, zp1 = 0.f;
            hp0 = dot2(tp[l32],       vp[l32],       hp0);
            hp1 = dot2(tp[l32 + 32],  vp[l32 + 32],  hp1);
            hp0 = dot2(tp[l32 + 64],  vp[l32 + 64],  hp0);
            hp1 = dot2(tp[l32 + 96],  vp[l32 + 96],  hp1);
            zp0 = dot2(tzp[l32],      pzp[l32],      zp0);
            zp1 = dot2(tzp[l32 + 32], pzp[l32 + 32], zp1);
            zp0 = dot2(tzp[l32 + 64], pzp[l32 + 64], zp0);
            zp1 = dot2(tzp[l32 + 96], pzp[l32 + 96], zp1);
            const h2* scp  = (const h2*)&sclh[rb][0];
            const h2* pzip = (const h2*)&pzi16[rr][0];
            zp0 = dot2(scp[l32], pzip[l32], zp0);
            float hp = hp0 + hp1, zp = zp0 + zp1;
            #pragma unroll
            for (int off = 16; off >= 1; off >>= 1) {
                hp += __shfl_xor(hp, off);
                zp += __shfl_xor(zp, off);
            }
            rzb = 0.99f * rzb + 0.01f * (zp + czb);
            const float sg = 1.0f / (1.0f + __expf(-rzb));
            if (l32 == 0) gl[rb][rr] = sg * hp;
        }

        // main dot2 partials, both batches, q-quadrant; 2 chains per batch
        {
            float az0a = 0.f, az0b = 0.f, az1a = 0.f, az1b = 0.f;
            float ah0 = 0.f, ah1 = 0.f;
            const uint4* tz0 = (const uint4*)&tzh[0][q << 6];
            const uint4* tz1 = (const uint4*)&tzh[1][q << 6];
            #pragma unroll
            for (int m = 0; m < 8; ++m) {
                const uint4 u0 = tz0[m];
                const uint4 u1 = tz1[m];
                az0a = dot2(wzzp[4 * m + 0], bc(u0.x), az0a);
                az0a = dot2(wzzp[4 * m + 1], bc(u0.y), az0a);
                az0b = dot2(wzzp[4 * m + 2], bc(u0.z), az0b);
                az0b = dot2(wzzp[4 * m + 3], bc(u0.w), az0b);
                az1a = dot2(wzzp[4 * m + 0], bc(u1.x), az1a);
                az1a = dot2(wzzp[4 * m + 1], bc(u1.y), az1a);
                az1b = dot2(wzzp[4 * m + 2], bc(u1.z), az1b);
                az1b = dot2(wzzp[4 * m + 3], bc(u1.w), az1b);
            }
            const uint4* sp0 = (const uint4*)&sclh[0][q << 4];
            const uint4* sp1 = (const uint4*)&sclh[1][q << 4];
            #pragma unroll
            for (int m = 0; m < 2; ++m) {
                const uint4 u0 = sp0[m];
                const uint4 u1 = sp1[m];
                az0a = dot2(wzip[4 * m + 0], bc(u0.x), az0a);
                az0a = dot2(wzip[4 * m + 1], bc(u0.y), az0a);
                az0b = dot2(wzip[4 * m + 2], bc(u0.z), az0b);
                az0b = dot2(wzip[4 * m + 3], bc(u0.w), az0b);
                az1a = dot2(wzip[4 * m + 0], bc(u1.x), az1a);
                az1a = dot2(wzip[4 * m + 1], bc(u1.y), az1a);
                az1b = dot2(wzip[4 * m + 2], bc(u1.z), az1b);
                az1b = dot2(wzip[4 * m + 3], bc(u1.w), az1b);
            }
            const uint4 uw0 = *(const uint4*)&sclh[0][q << 3];
            const uint4 uw1 = *(const uint4*)&sclh[1][q << 3];
            ah0 = dot2(wip[0], bc(uw0.x), ah0);
            ah0 = dot2(wip[1], bc(uw0.y), ah0);
            ah0 = dot2(wip[2], bc(uw0.z), ah0);
            ah0 = dot2(wip[3], bc(uw0.w), ah0);
            ah1 = dot2(wip[0], bc(uw1.x), ah1);
            ah1 = dot2(wip[1], bc(uw1.y), ah1);
            ah1 = dot2(wip[2], bc(uw1.z), ah1);
            ah1 = dot2(wip[3], bc(uw1.w), ah1);
            redz[q][0][i] = az0a + az0b;
            redz[q][1][i] = az1a + az1b;
            redh[q][0][i] = ah0;
            redh[q][1][i] = ah1;
        }
        __syncthreads();  // B

        // ================= B..A' =================
        if (!hi) {
            // z-update: bb = q (0..1)
            const int bb = q;
            const float tmp = redz[0][bb][i] + redz[1][bb][i]
                            + redz[2][bb][i] + redz[3][bb][i] + bias_r;
            state_r = 0.99f * state_r + 0.01f * tmp;
            tzh[bb][i] = (f16)fast_tanh(state_r);
            states[((size_t)t * BATCH + b0 + bb) * 512 + i] = state_r;
        } else {
            // h-update: bb = q-2 (0..1); consumes gl published in phase A
            const int bb = q - 2;
            float t0 = redh[0][bb][i] + redh[1][bb][i]
                     + redh[2][bb][i] + redh[3][bb][i] + bias_r;
            float t1 = 0.f;
            #pragma unroll
            for (int r = 0; r < 4; ++r) {
                t0 = fmaf((float)ut16[2 * r][i],     gl[bb][2 * r],     t0);
                t1 = fmaf((float)ut16[2 * r + 1][i], gl[bb][2 * r + 1], t1);
            }
            state_r = 0.9f * state_r + 0.1f * (t0 + t1);
            thh[bb][i] = (f16)fast_tanh(state_r);
            states[((size_t)t * BATCH + b0 + bb) * 512 + 256 + i] = state_r;
        }
        if (tid < 128 && t + 1 < T_STEPS)
            sclh[tid >> 6][tid & 63] = (f16)pfn;
        __syncthreads();  // A
    }

    // ---- final out (t = T_STEPS-1) ----
    {
        const h2* tp = (const h2*)&thh[ob][0];
        const h2* wp = (const h2*)&wo16[oy][0];
        float o0 = 0.f, o1 = 0.f;
        o0 = dot2(tp[l32],      wp[l32],      o0);
        o1 = dot2(tp[l32 + 32], wp[l32 + 32], o1);
        o0 = dot2(tp[l32 + 64], wp[l32 + 64], o0);
        o1 = dot2(tp[l32 + 96], wp[l32 + 96], o1);
        float o = o0 + o1;
        #pragma unroll
        for (int off = 16; off >= 1; off >>= 1) o += __shfl_xor(o, off);
        if (l32 == 0)
            out[((size_t)(T_STEPS - 1) * BATCH + b0 + ob) * 16 + oy] = o + bo[oy];
    }
}

extern "C" void kernel_launch(void* const* d_in, const int* in_sizes, int n_in,
                              void* d_out, int out_size, void* d_ws, size_t ws_size,
                              hipStream_t stream) {
    const float* s     = (const float*)d_in[0];
    const float* c     = (const float*)d_in[1];
    const float* W_zz  = (const float*)d_in[2];
    const float* Wz_in = (const float*)d_in[3];
    const float* bz_in = (const float*)d_in[4];
    const float* Wz_out= (const float*)d_in[5];
    const float* bz_out= (const float*)d_in[6];
    const float* U     = (const float*)d_in[7];
    const float* V     = (const float*)d_in[8];
    const float* W_in  = (const float*)d_in[9];
    const float* b_in  = (const float*)d_in[10];
    const float* W_out = (const float*)d_in[11];
    const float* b_out = (const float*)d_in[12];

    float* out    = (float*)d_out;
    float* states = out + (size_t)T_STEPS * BATCH * DY;

    hipLaunchKernelGGL(nmrnn_kernel, dim3(BATCH / 2), dim3(1024), 0, stream,
                       s, c, W_zz, Wz_in, bz_in, Wz_out, bz_out, U, V,
                       W_in, b_in, W_out, b_out, out, states);
}